// Round 1
// baseline (171.636 us; speedup 1.0000x reference)
//
#include <hip/hip_runtime.h>

#define HIDDEN 128
#define RNA_NUM_C 20000
#define DIS_TILE 16

// ---------------------------------------------------------------------------
// Kernel 1: normalize rna rows: out[i] = emb[i] / (||emb[i]||_2 + 0.1)
// One 64-lane wave per row; each lane holds 2 floats (float2 = full 512B row).
// ---------------------------------------------------------------------------
__global__ __launch_bounds__(256) void k_norm_rna(const float* __restrict__ emb,
                                                  float* __restrict__ out,
                                                  int nrows) {
    int w    = (blockIdx.x * blockDim.x + threadIdx.x) >> 6;   // wave id = row
    int lane = threadIdx.x & 63;
    if (w >= nrows) return;
    float2 v = ((const float2*)(emb + (size_t)w * HIDDEN))[lane];
    float ss = v.x * v.x + v.y * v.y;
#pragma unroll
    for (int m = 1; m < 64; m <<= 1) ss += __shfl_xor(ss, m, 64);
    float sc = 1.0f / (sqrtf(ss) + 0.1f);
    float2 o; o.x = v.x * sc; o.y = v.y * sc;
    ((float2*)(out + (size_t)w * HIDDEN))[lane] = o;
}

// ---------------------------------------------------------------------------
// Kernel 2: U[j][h] = (1/(||dis_j||+0.1)) * sum_k dis_raw[j][k] * We[h][k]
// Block = 256 threads, DIS_TILE=16 dis rows per block.
// We staged TRANSPOSED in LDS with stride 129:
//   - transpose-write: within a wave h is uniform, k = consecutive lanes
//     -> addr k*129+h -> consecutive banks -> conflict-free
//   - read: k uniform, h consecutive across lanes -> conflict-free
// dis reads in the FMA loop are wave-uniform (broadcast, free).
// ---------------------------------------------------------------------------
__global__ __launch_bounds__(256) void k_dis_transform(
        const float* __restrict__ emb,   // dis rows start at RNA_NUM_C
        const float* __restrict__ We,    // [128][128] row-major
        float* __restrict__ U,           // [dis_num][128]
        int dis_num) {
    __shared__ float WeT[128 * 129];
    __shared__ float ds[DIS_TILE * 128];
    __shared__ float sc[DIS_TILE];
    int t = threadIdx.x;

    // stage We transposed (scalar, conflict-free pattern)
#pragma unroll
    for (int i = 0; i < 64; ++i) {
        int idx = t + i * 256;
        int h = idx >> 7, k = idx & 127;
        WeT[k * 129 + h] = We[idx];
    }
    // stage dis tile (float4 coalesced)
    int jb = blockIdx.x * DIS_TILE;
#pragma unroll
    for (int i = 0; i < 2; ++i) {
        int idx4 = t + i * 256;
        int j = idx4 >> 5, k4 = idx4 & 31;
        int jg = jb + j;
        float4 v = make_float4(0.f, 0.f, 0.f, 0.f);
        if (jg < dis_num)
            v = ((const float4*)(emb + (size_t)(RNA_NUM_C + jg) * HIDDEN))[k4];
        *((float4*)(ds + j * 128 + 4 * k4)) = v;
    }
    __syncthreads();

    // per-row inverse (norm + 0.1): 16 lanes per row
    {
        int row = t >> 4, l16 = t & 15;
        float ssum = 0.f;
#pragma unroll
        for (int c = 0; c < 8; ++c) {
            float x = ds[row * 128 + l16 * 8 + c];
            ssum += x * x;
        }
#pragma unroll
        for (int m = 1; m < 16; m <<= 1) ssum += __shfl_xor(ssum, m, 16);
        if (l16 == 0) sc[row] = 1.0f / (sqrtf(ssum) + 0.1f);
    }
    __syncthreads();

    // each thread: fixed output column h, 8 rows
    int h = t & 127, j0 = t >> 7;
    float acc[8];
#pragma unroll
    for (int jj = 0; jj < 8; ++jj) acc[jj] = 0.f;
#pragma unroll 4
    for (int k = 0; k < 128; ++k) {
        float w = WeT[k * 129 + h];
#pragma unroll
        for (int jj = 0; jj < 8; ++jj)
            acc[jj] += w * ds[(j0 * 8 + jj) * 128 + k];
    }
#pragma unroll
    for (int jj = 0; jj < 8; ++jj) {
        int j = j0 * 8 + jj;
        int jg = jb + j;
        if (jg < dis_num)
            U[(size_t)jg * HIDDEN + h] = acc[jj] * sc[j];
    }
}

// ---------------------------------------------------------------------------
// Kernel 3: per-edge gather-dot. One edge per 32-lane half-wave.
// Each lane: one float4 of rna row + one float4 of U row (coalesced 512B rows),
// 4-wide FMA, then 5-step shuffle reduce within the 32-lane group.
// ---------------------------------------------------------------------------
__global__ __launch_bounds__(256) void k_edges(
        const float* __restrict__ rna,   // normalized [RNA_NUM][128]
        const float* __restrict__ U,     // [DIS_NUM][128]
        const int* __restrict__ pr, const int* __restrict__ pd,
        const int* __restrict__ nr, const int* __restrict__ nd,
        float* __restrict__ out, int epos, int etot) {
    int g = (blockIdx.x * blockDim.x + threadIdx.x) >> 5;
    if (g >= etot) return;
    int lane = threadIdx.x & 31;
    int ridx, didx;
    if (g < epos) { ridx = pr[g];        didx = pd[g]; }
    else          { ridx = nr[g - epos]; didx = nd[g - epos]; }
    float4 a = ((const float4*)(rna + (size_t)ridx * HIDDEN))[lane];
    float4 b = ((const float4*)(U   + (size_t)didx * HIDDEN))[lane];
    float s = a.x * b.x + a.y * b.y + a.z * b.z + a.w * b.w;
#pragma unroll
    for (int m = 1; m < 32; m <<= 1) s += __shfl_xor(s, m, 32);
    if (lane == 0) out[g] = s;
}

// ---------------------------------------------------------------------------
// Kernel 4: labels = [ones(epos), zeros(eneg)] written vectorized.
// ---------------------------------------------------------------------------
__global__ __launch_bounds__(256) void k_labels(float* __restrict__ out,
                                                int epos, int etot) {
    int i = blockIdx.x * blockDim.x + threadIdx.x;
    int i0 = i * 4;
    if (i0 >= etot) return;
    float4 v;
    v.x = (i0 + 0) < epos ? 1.0f : 0.0f;
    v.y = (i0 + 1) < epos ? 1.0f : 0.0f;
    v.z = (i0 + 2) < epos ? 1.0f : 0.0f;
    v.w = (i0 + 3) < epos ? 1.0f : 0.0f;
    ((float4*)(out + etot))[i] = v;   // etot*4 bytes is 16B-aligned (etot%4==0)
}

extern "C" void kernel_launch(void* const* d_in, const int* in_sizes, int n_in,
                              void* d_out, int out_size, void* d_ws, size_t ws_size,
                              hipStream_t stream) {
    const float* emb = (const float*)d_in[0];
    const float* We  = (const float*)d_in[1];
    const int*   pr  = (const int*)d_in[2];
    const int*   pd  = (const int*)d_in[3];
    const int*   nr  = (const int*)d_in[4];
    const int*   nd  = (const int*)d_in[5];
    float* out = (float*)d_out;

    int epos = in_sizes[2];
    int eneg = in_sizes[4];
    int etot = epos + eneg;
    int total_rows = in_sizes[0] / HIDDEN;
    int dis_num = total_rows - RNA_NUM_C;   // reference fixes rna_num = 20000

    float* ws_rna = (float*)d_ws;                              // 20000*128 f32
    float* U      = ws_rna + (size_t)RNA_NUM_C * HIDDEN;       //  5000*128 f32

    // 1) normalize rna rows (4 rows / 256-thread block)
    k_norm_rna<<<(RNA_NUM_C + 3) / 4, 256, 0, stream>>>(emb, ws_rna, RNA_NUM_C);
    // 2) normalize+transform dis rows: U = (dis/||dis||+0.1) @ We^T
    k_dis_transform<<<(dis_num + DIS_TILE - 1) / DIS_TILE, 256, 0, stream>>>(
        emb, We, U, dis_num);
    // 3) per-edge gather-dot (8 edges per 256-thread block)
    k_edges<<<(etot + 7) / 8, 256, 0, stream>>>(ws_rna, U, pr, pd, nr, nd,
                                                out, epos, etot);
    // 4) labels
    k_labels<<<(etot / 4 + 255) / 256, 256, 0, stream>>>(out, epos, etot);
}

// Round 2
// 129.915 us; speedup vs baseline: 1.3211x; 1.3211x over previous
//
#include <hip/hip_runtime.h>
#include <hip/hip_bf16.h>

#define HIDDEN 128
#define RNA_NUM_C 20000
#define DIS_TILE 16

// ---------------------------------------------------------------------------
// Kernel 1: normalize ALL rows: v = emb[i] / (||emb[i]|| + 0.1).
// rna rows (i < 20000) -> bf16 table (gather side, shrinks L2 working set 2x)
// dis rows (i >= 20000) -> f32 scratch (input to the U transform)
// One 64-lane wave per row, float2 per lane.
// ---------------------------------------------------------------------------
__global__ __launch_bounds__(256) void k_norm(const float* __restrict__ emb,
                                              __hip_bfloat162* __restrict__ rna_bf,
                                              float* __restrict__ dis_norm,
                                              int total_rows) {
    int w    = (blockIdx.x * blockDim.x + threadIdx.x) >> 6;
    int lane = threadIdx.x & 63;
    if (w >= total_rows) return;
    float2 v = ((const float2*)(emb + (size_t)w * HIDDEN))[lane];
    float ss = v.x * v.x + v.y * v.y;
#pragma unroll
    for (int m = 1; m < 64; m <<= 1) ss += __shfl_xor(ss, m, 64);
    float sc = 1.0f / (sqrtf(ss) + 0.1f);
    float ox = v.x * sc, oy = v.y * sc;
    if (w < RNA_NUM_C) {
        __hip_bfloat162 p;
        p.x = __float2bfloat16(ox);
        p.y = __float2bfloat16(oy);
        rna_bf[(size_t)w * 64 + lane] = p;
    } else {
        float2 o; o.x = ox; o.y = oy;
        ((float2*)(dis_norm + (size_t)(w - RNA_NUM_C) * HIDDEN))[lane] = o;
    }
}

// ---------------------------------------------------------------------------
// Kernel 2: U[j][h] = sum_k dis_norm[j][k] * We[h][k], output bf16.
// Block = 256 threads, 16 dis rows per block.
// WeT staged transposed (stride 129 -> conflict-free both directions).
// FMA loop: k in chunks of 4; WeT b32 reads conflict-free, ds float4 reads
// are wave-uniform broadcasts. ~3x fewer LDS instructions than round 1.
// ---------------------------------------------------------------------------
__global__ __launch_bounds__(256) void k_dis_u(
        const float* __restrict__ dis_norm,
        const float* __restrict__ We,     // [128][128] row-major
        __hip_bfloat16* __restrict__ U_bf,
        int dis_num) {
    __shared__ float WeT[128 * 129];
    __shared__ float ds[DIS_TILE * 128];
    int t = threadIdx.x;

#pragma unroll
    for (int i = 0; i < 64; ++i) {
        int idx = t + i * 256;
        int h = idx >> 7, k = idx & 127;
        WeT[k * 129 + h] = We[idx];
    }
    int jb = blockIdx.x * DIS_TILE;
#pragma unroll
    for (int i = 0; i < 2; ++i) {
        int idx4 = t + i * 256;
        int j = idx4 >> 5, k4 = idx4 & 31;
        int jg = jb + j;
        float4 v = make_float4(0.f, 0.f, 0.f, 0.f);
        if (jg < dis_num)
            v = ((const float4*)(dis_norm + (size_t)jg * HIDDEN))[k4];
        *((float4*)(ds + j * 128 + 4 * k4)) = v;
    }
    __syncthreads();

    int h = t & 127, j0 = t >> 7;     // j0 in {0,1}; rows j0*8 + jj
    float acc[8];
#pragma unroll
    for (int jj = 0; jj < 8; ++jj) acc[jj] = 0.f;
    for (int k = 0; k < 128; k += 4) {
        float w0 = WeT[(k + 0) * 129 + h];
        float w1 = WeT[(k + 1) * 129 + h];
        float w2 = WeT[(k + 2) * 129 + h];
        float w3 = WeT[(k + 3) * 129 + h];
#pragma unroll
        for (int jj = 0; jj < 8; ++jj) {
            float4 d4 = *((const float4*)(ds + (j0 * 8 + jj) * 128 + k));
            acc[jj] += w0 * d4.x + w1 * d4.y + w2 * d4.z + w3 * d4.w;
        }
    }
#pragma unroll
    for (int jj = 0; jj < 8; ++jj) {
        int jg = jb + j0 * 8 + jj;
        if (jg < dis_num)
            U_bf[(size_t)jg * HIDDEN + h] = __float2bfloat16(acc[jj]);
    }
}

// ---------------------------------------------------------------------------
// Kernel 3: per-edge gather-dot in bf16. 16 lanes per edge; each lane loads
// one uint4 (8 bf16) from each table (256B coalesced row reads), converts via
// bit ops (exact), f32 FMA, 4-step shuffle reduce within the 16-lane group.
// ---------------------------------------------------------------------------
__device__ __forceinline__ float bdot(unsigned u, unsigned v) {
    float ulo = __uint_as_float(u << 16);
    float uhi = __uint_as_float(u & 0xffff0000u);
    float vlo = __uint_as_float(v << 16);
    float vhi = __uint_as_float(v & 0xffff0000u);
    return ulo * vlo + uhi * vhi;
}

__global__ __launch_bounds__(256) void k_edges(
        const uint4* __restrict__ rna_bf,   // row = 16 x uint4 (256B)
        const uint4* __restrict__ U_bf,
        const int* __restrict__ pr, const int* __restrict__ pd,
        const int* __restrict__ nr, const int* __restrict__ nd,
        float* __restrict__ out, int epos, int etot) {
    int tid = blockIdx.x * blockDim.x + threadIdx.x;
    int g = tid >> 4;
    if (g >= etot) return;
    int l = tid & 15;
    int ridx, didx;
    if (g < epos) { ridx = pr[g];        didx = pd[g]; }
    else          { ridx = nr[g - epos]; didx = nd[g - epos]; }
    uint4 a = rna_bf[(size_t)ridx * 16 + l];
    uint4 b = U_bf[(size_t)didx * 16 + l];
    float s = bdot(a.x, b.x) + bdot(a.y, b.y) + bdot(a.z, b.z) + bdot(a.w, b.w);
#pragma unroll
    for (int m = 1; m < 16; m <<= 1) s += __shfl_xor(s, m, 64);
    if (l == 0) out[g] = s;
}

// ---------------------------------------------------------------------------
// Kernel 4: labels = [ones(epos), zeros(eneg)], float4 stores.
// ---------------------------------------------------------------------------
__global__ __launch_bounds__(256) void k_labels(float* __restrict__ out,
                                                int epos, int etot) {
    int i = blockIdx.x * blockDim.x + threadIdx.x;
    int i0 = i * 4;
    if (i0 >= etot) return;
    float4 v;
    v.x = (i0 + 0) < epos ? 1.0f : 0.0f;
    v.y = (i0 + 1) < epos ? 1.0f : 0.0f;
    v.z = (i0 + 2) < epos ? 1.0f : 0.0f;
    v.w = (i0 + 3) < epos ? 1.0f : 0.0f;
    ((float4*)(out + etot))[i] = v;
}

extern "C" void kernel_launch(void* const* d_in, const int* in_sizes, int n_in,
                              void* d_out, int out_size, void* d_ws, size_t ws_size,
                              hipStream_t stream) {
    const float* emb = (const float*)d_in[0];
    const float* We  = (const float*)d_in[1];
    const int*   pr  = (const int*)d_in[2];
    const int*   pd  = (const int*)d_in[3];
    const int*   nr  = (const int*)d_in[4];
    const int*   nd  = (const int*)d_in[5];
    float* out = (float*)d_out;

    int epos = in_sizes[2];
    int eneg = in_sizes[4];
    int etot = epos + eneg;
    int total_rows = in_sizes[0] / HIDDEN;
    int dis_num = total_rows - RNA_NUM_C;

    // workspace layout (bytes from d_ws):
    //   rna_bf   : 20000*128*2 = 5.12 MB
    //   U_bf     :  5000*128*2 = 1.28 MB
    //   dis_norm :  5000*128*4 = 2.56 MB
    char* wsb = (char*)d_ws;
    __hip_bfloat162* rna_bf = (__hip_bfloat162*)wsb;
    __hip_bfloat16*  U_bf   = (__hip_bfloat16*)(wsb + (size_t)RNA_NUM_C * HIDDEN * 2);
    float* dis_norm = (float*)(wsb + (size_t)RNA_NUM_C * HIDDEN * 2
                                   + (size_t)dis_num * HIDDEN * 2);

    // 1) normalize all rows (4 waves/block, 1 row/wave)
    int nwaves = total_rows;
    k_norm<<<(nwaves + 3) / 4, 256, 0, stream>>>(emb, rna_bf, dis_norm, total_rows);
    // 2) U = dis_norm @ We^T  (bf16 out)
    k_dis_u<<<(dis_num + DIS_TILE - 1) / DIS_TILE, 256, 0, stream>>>(
        dis_norm, We, U_bf, dis_num);
    // 3) per-edge gather-dot (16 edges / 256-thread block)
    k_edges<<<(etot + 15) / 16, 256, 0, stream>>>(
        (const uint4*)rna_bf, (const uint4*)U_bf, pr, pd, nr, nd, out, epos, etot);
    // 4) labels
    k_labels<<<(etot / 4 + 255) / 256, 256, 0, stream>>>(out, epos, etot);
}